// Round 3
// baseline (171.365 us; speedup 1.0000x reference)
//
#include <hip/hip_runtime.h>
#include <hip/hip_bf16.h>
#include <math.h>

#define KK 5
#define KN 32
#define CIN 16
#define H 64
#define W 64
#define NB 32
#define HO 60
#define WO 60
#define D_TOT 400
#define OUT_PLANE (NB*HO*WO*KN)

// block tile: 8 out-rows x 16 out-cols, 4 waves, each wave 2 rows (one 32x32 MFMA tile)
#define TH 8
#define TW 16
#define IN_R 12      // TH + KK - 1
#define IN_C 20      // TW + KK - 1
#define CPAD 24      // c padded 16 -> 24 shorts (48B col stride)
#define TILE_SH (IN_R*IN_C*CPAD)   // 5760 shorts per map
#define NPOS 25                    // 5x5 kernel positions, K=16 each
#define NBLK (4*8*NB)              // 1024 blocks total

typedef short short8 __attribute__((ext_vector_type(8)));
typedef float f32x16 __attribute__((ext_vector_type(16)));

// ---- device globals: B-pack + ticket/done/fin sync (self-resetting) ----
__device__ ushort g_bmu[NPOS * 64 * 8];   // 12800 shorts
__device__ ushort g_bsq[NPOS * 64 * 8];   // 12800 shorts
__device__ int g_ticket = 0;
__device__ int g_done   = 0;
__device__ int g_fin    = 0;

__device__ __forceinline__ ushort f2bf(float x) {
    __hip_bfloat16 h = __float2bfloat16(x);
    return *reinterpret_cast<ushort*>(&h);
}
__device__ __forceinline__ float softplusf(float x) {
    return (x > 20.0f) ? x : __logf(1.0f + __expf(x));
}

// ---------------- single fused kernel ----------------
// Ticket scheme (dispatch-order-proof): first 25 blocks to START take tickets
// 0..24 and pack position ts=ticket into g_bmu/g_bsq (no waiting before
// packing -> deadlock-free with any >=26 blocks ever running). Ticket 25
// computes KL. All blocks spin on g_done>=25 only AFTER their own staging+t12,
// so the wait is expected to be ~zero. g_ticket/g_done/g_fin self-reset by the
// last block to finish (same-stream ordering covers the next launch).
__global__ __launch_bounds__(256, 4)
void vdp_fused(const float* __restrict__ mu_in, const float* __restrict__ sig_in,
               const float* __restrict__ w_mu, const float* __restrict__ w_sigma,
               float* __restrict__ mu_out, float* __restrict__ sig_out,
               float* __restrict__ kl_out) {
    __shared__ ushort tiles[2 * TILE_SH];
    __shared__ float csum[IN_R * IN_C];   // per input pixel: sum_c (sigma + mu^2)
    __shared__ float t12s[TH * TW];
    __shared__ float s_spw[KN];
    __shared__ float red[256];
    __shared__ int s_tk;

    const int b   = blockIdx.z;
    const int ho0 = blockIdx.y * TH;
    const int wo0 = blockIdx.x * TW;
    const int t   = threadIdx.x;

    if (t == 0)
        s_tk = __hip_atomic_fetch_add(&g_ticket, 1, __ATOMIC_RELAXED,
                                      __HIP_MEMORY_SCOPE_AGENT);
    __syncthreads();
    const int tk = s_tk;

    if (tk < NPOS) {
        // ---- pack B fragments for position ts = tk ----
        // frag lane l, elem j: cin = (l>>5)*8+j, n = l&31
        if (t < 128) {
            const int l = t & 63, hi = l >> 5, n = l & 31;
            const float* wp = w_mu + tk * 512 + hi * 256 + n;
            float wv[8];
#pragma unroll
            for (int j = 0; j < 8; ++j) wv[j] = wp[j * 32];
            short8 fr;
            if (t < 64) {
#pragma unroll
                for (int j = 0; j < 8; ++j) fr[j] = (short)f2bf(wv[j]);
                *(short8*)&g_bmu[(tk * 64 + l) * 8] = fr;
            } else {
#pragma unroll
                for (int j = 0; j < 8; ++j)
                    fr[j] = (short)f2bf(wv[j] * wv[j] * (1.0f / 400.0f));
                *(short8*)&g_bsq[(tk * 64 + l) * 8] = fr;
            }
        }
        __threadfence();          // device-scope release of the pack stores
        __syncthreads();
        if (t == 0)
            __hip_atomic_fetch_add(&g_done, 1, __ATOMIC_RELEASE,
                                   __HIP_MEMORY_SCOPE_AGENT);
    } else if (tk == NPOS) {
        // ---- KL reduction (this block also does its normal tile work) ----
        float s = 0.f;
        for (int i = t; i < D_TOT * KN; i += 256) { float wv = w_mu[i]; s += wv * wv; }
        red[t] = s;
        __syncthreads();
        for (int off = 128; off > 0; off >>= 1) {
            if (t < off) red[t] += red[t + off];
            __syncthreads();
        }
        if (t == 0) {
            float sum_w2 = red[0];
            float sws = 0.f;
            for (int kn = 0; kn < KN; ++kn) {
                float ws = w_sigma[kn];
                float sp = log1pf(expf(ws));
                sws += -ws + sp * 100.0f;
            }
            *kl_out = 0.5f * (-4.605170186f - 1.0f + sws * (1.0f / 32.0f)
                              + sum_w2 * (100.0f / 12800.0f));
        }
    }

    // ---- per-block softplus(w_sigma)/400 ----
    if (t < KN) s_spw[t] = log1pf(expf(w_sigma[t])) * (1.0f / 400.0f);

    // ---- stage 12x20x16 fp32 -> bf16 LDS, with fused per-pixel channel sums ----
    for (int i = t; i < IN_R * IN_C * 4; i += 256) {   // 960 iters
        int pix = i >> 2, c4 = i & 3;
        int row = pix / IN_C;
        int col = pix - row * IN_C;
        int gh = ho0 + row, gw = wo0 + col;
        float4 vm = make_float4(0.f, 0.f, 0.f, 0.f), vs = vm;
        if (gh < H && gw < W) {
            size_t g = (((size_t)b * H + gh) * W + gw) * CIN + c4 * 4;
            vm = *(const float4*)(mu_in + g);
            vs = *(const float4*)(sig_in + g);
        }
        int sb = pix * CPAD + c4 * 4;
        ushort4 um, us;
        um.x = f2bf(vm.x); um.y = f2bf(vm.y); um.z = f2bf(vm.z); um.w = f2bf(vm.w);
        us.x = f2bf(vs.x); us.y = f2bf(vs.y); us.z = f2bf(vs.z); us.w = f2bf(vs.w);
        *(ushort4*)&tiles[sb] = um;
        *(ushort4*)&tiles[TILE_SH + sb] = us;
        float part = vs.x + vs.y + vs.z + vs.w
                   + vm.x * vm.x + vm.y * vm.y + vm.z * vm.z + vm.w * vm.w;
        part += __shfl_down(part, 2, 4);
        part += __shfl_down(part, 1, 4);
        if (c4 == 0) csum[pix] = part;
    }
    __syncthreads();

    // ---- 5x5 window sums: t12 per output pixel ----
    if (t < TH * TW) {
        int r = t >> 4, c = t & 15;
        float s = 0.f;
#pragma unroll
        for (int kh = 0; kh < KK; ++kh)
#pragma unroll
            for (int kw = 0; kw < KK; ++kw)
                s += csum[(r + kh) * IN_C + c + kw];
        t12s[t] = s;
    }
    __syncthreads();

    // ---- wait for B-pack completion (expected already done) ----
    if (t == 0) {
        while (__hip_atomic_load(&g_done, __ATOMIC_ACQUIRE,
                                 __HIP_MEMORY_SCOPE_AGENT) < NPOS)
            __builtin_amdgcn_s_sleep(2);
    }
    __syncthreads();

    // ---- MFMA k-loop: 25 positions, K=16 channels each, 32x32x16 ----
    const int w   = t >> 6;          // wave id: rows 2w, 2w+1
    const int l   = t & 63;
    const int p   = l & 31;          // pixel index within wave's 32-px tile
    const int hi  = l >> 5;          // channel half for A/B k-elements
    const int pr  = p >> 4;          // local row 0/1
    const int pc  = p & 15;          // col 0..15

    const char* lds = (const char*)tiles;
    const int abase = ((2 * w + pr) * IN_C + pc) * (CPAD * 2) + hi * 16;

    const short8* Bmu8 = (const short8*)g_bmu;
    const short8* Bsq8 = (const short8*)g_bsq;

    f32x16 accm = {0.f}, accs = {0.f};
#pragma unroll
    for (int kh = 0; kh < KK; ++kh) {
#pragma unroll
        for (int kw = 0; kw < KK; ++kw) {
            const int ts  = kh * KK + kw;
            const int off = (kh * IN_C + kw) * (CPAD * 2);
            short8 am = *(const short8*)(lds + abase + off);
            short8 as = *(const short8*)(lds + abase + off + TILE_SH * 2);
            short8 bm = Bmu8[ts * 64 + l];
            short8 bs = Bsq8[ts * 64 + l];
            accm = __builtin_amdgcn_mfma_f32_32x32x16_bf16(am, bm, accm, 0, 0, 0);
            accs = __builtin_amdgcn_mfma_f32_32x32x16_bf16(as, bs, accs, 0, 0, 0);
        }
    }

    // ---- epilogue ----
    // D: col(channel) = l&31, row(pixel) = (reg&3) + 8*(reg>>2) + 4*hi
    const int n = l & 31;
    const float spwn = s_spw[n];
#pragma unroll
    for (int reg = 0; reg < 16; ++reg) {
        int rloc = (reg & 3) + 8 * (reg >> 2) + 4 * hi;   // pixel 0..31
        int lr = rloc >> 4, lc = rloc & 15;
        int ho = ho0 + 2 * w + lr;
        int wo = wo0 + lc;
        if (ho < HO && wo < WO) {
            float t12v = t12s[(2 * w + lr) * TW + lc];
            size_t base = (((size_t)b * HO + ho) * WO + wo) * KN + n;
            mu_out[base]  = accm[reg];
            sig_out[base] = softplusf(accs[reg] + t12v * spwn);
        }
    }

    // ---- self-reset for next launch (last finishing block) ----
    __syncthreads();
    if (t == 0) {
        int f = __hip_atomic_fetch_add(&g_fin, 1, __ATOMIC_ACQ_REL,
                                       __HIP_MEMORY_SCOPE_AGENT);
        if (f == NBLK - 1) {
            __hip_atomic_store(&g_ticket, 0, __ATOMIC_RELAXED, __HIP_MEMORY_SCOPE_AGENT);
            __hip_atomic_store(&g_done,   0, __ATOMIC_RELAXED, __HIP_MEMORY_SCOPE_AGENT);
            __hip_atomic_store(&g_fin,    0, __ATOMIC_RELAXED, __HIP_MEMORY_SCOPE_AGENT);
        }
    }
}

extern "C" void kernel_launch(void* const* d_in, const int* in_sizes, int n_in,
                              void* d_out, int out_size, void* d_ws, size_t ws_size,
                              hipStream_t stream) {
    const float* mu_in   = (const float*)d_in[0];
    const float* sig_in  = (const float*)d_in[1];
    const float* w_mu    = (const float*)d_in[2];
    const float* w_sigma = (const float*)d_in[3];

    float* out     = (float*)d_out;
    float* mu_out  = out;
    float* sig_out = out + (size_t)OUT_PLANE;
    float* kl_out  = out + 2 * (size_t)OUT_PLANE;

    (void)d_ws; (void)ws_size;

    vdp_fused<<<dim3(4, 8, NB), 256, 0, stream>>>(mu_in, sig_in, w_mu, w_sigma,
                                                  mu_out, sig_out, kl_out);
}

// Round 4
// 114.038 us; speedup vs baseline: 1.5027x; 1.5027x over previous
//
#include <hip/hip_runtime.h>
#include <hip/hip_bf16.h>
#include <math.h>

#define KK 5
#define KN 32
#define CIN 16
#define H 64
#define W 64
#define NB 32
#define HO 60
#define WO 60
#define D_TOT 400
#define OUT_PLANE (NB*HO*WO*KN)

// block tile: 8 out-rows x 16 out-cols, 4 waves, each wave 2 rows (one 32x32 MFMA tile)
#define TH 8
#define TW 16
#define IN_R 12      // TH + KK - 1
#define IN_C 20      // TW + KK - 1
#define CPAD 24      // c padded 16 -> 24 shorts (48B col stride)
#define TILE_SH (IN_R*IN_C*CPAD)   // 5760 shorts per map
#define NPOS 25                    // 5x5 kernel positions, K=16 each

typedef short short8 __attribute__((ext_vector_type(8)));
typedef float f32x16 __attribute__((ext_vector_type(16)));

// ---- module-scope device globals (workspace unused; fills are unconditional anyway) ----
__device__ ushort g_bmu[NPOS * 64 * 8];   // 12800 shorts
__device__ ushort g_bsq[NPOS * 64 * 8];   // 12800 shorts
__device__ float  g_spw[KN];

__device__ __forceinline__ ushort f2bf(float x) {
    __hip_bfloat16 h = __float2bfloat16(x);
    return *reinterpret_cast<ushort*>(&h);
}
__device__ __forceinline__ float softplusf(float x) {
    return (x > 20.0f) ? x : __logf(1.0f + __expf(x));
}

// ---------------- prep: pack B fragments (32x32x16 layout) + spw + KL ----------------
// frag for position ts (=kh*5+kw), lane l, elem j:
//   cin = (l>>5)*8 + j ; n = l&31 ; w index = ts*512 + cin*32 + n
__global__ void prep_all(const float* __restrict__ w_mu, const float* __restrict__ w_sigma,
                         float* __restrict__ kl_out) {
    __shared__ float red[256];
    int t = threadIdx.x;
    if (blockIdx.x < 50) {
        int idx = blockIdx.x * 256 + t;     // < 12800
        int j  = idx & 7;
        int l  = (idx >> 3) & 63;
        int ts = idx >> 9;
        int cin = ((l >> 5) & 1) * 8 + j;
        int n   = l & 31;
        float w = w_mu[ts * 512 + cin * 32 + n];
        g_bmu[idx] = f2bf(w);
        g_bsq[idx] = f2bf(w * w * (1.0f / 400.0f));
    } else {
        // KL + spw block
        float s = 0.f;
        for (int i = t; i < D_TOT * KN; i += 256) { float w = w_mu[i]; s += w * w; }
        red[t] = s;
        __syncthreads();
        for (int off = 128; off > 0; off >>= 1) {
            if (t < off) red[t] += red[t + off];
            __syncthreads();
        }
        float sum_w2 = red[0];
        if (t < KN) {
            float ws = w_sigma[t];
            g_spw[t] = log1pf(expf(ws)) * (1.0f / 400.0f);
        }
        if (t == 0) {
            float sws = 0.f;
            for (int kn = 0; kn < KN; ++kn) {
                float ws = w_sigma[kn];
                float sp = log1pf(expf(ws));
                sws += -ws + sp * 100.0f;
            }
            float kl = 0.5f * (-4.605170186f - 1.0f + sws * (1.0f / 32.0f)
                               + sum_w2 * (100.0f / 12800.0f));
            *kl_out = kl;
        }
    }
}

// ---------------- main ----------------
__global__ __launch_bounds__(256, 4)
void vdp_main(const float* __restrict__ mu_in, const float* __restrict__ sig_in,
              float* __restrict__ mu_out, float* __restrict__ sig_out) {
    __shared__ ushort tiles[2 * TILE_SH];
    __shared__ float csum[IN_R * IN_C];   // per input pixel: sum_c (sigma + mu^2)
    __shared__ float t12s[TH * TW];

    const int b   = blockIdx.z;
    const int ho0 = blockIdx.y * TH;
    const int wo0 = blockIdx.x * TW;
    const int t   = threadIdx.x;

    // ---- stage 12x20x16 fp32 -> bf16 LDS, with fused per-pixel channel sums ----
    // i = pix*4 + c4 ; quad of consecutive lanes covers one pixel's 16 channels
    for (int i = t; i < IN_R * IN_C * 4; i += 256) {   // 960 iters
        int pix = i >> 2, c4 = i & 3;
        int row = pix / IN_C;
        int col = pix - row * IN_C;
        int gh = ho0 + row, gw = wo0 + col;
        float4 vm = make_float4(0.f, 0.f, 0.f, 0.f), vs = vm;
        if (gh < H && gw < W) {
            size_t g = (((size_t)b * H + gh) * W + gw) * CIN + c4 * 4;
            vm = *(const float4*)(mu_in + g);
            vs = *(const float4*)(sig_in + g);
        }
        int sb = pix * CPAD + c4 * 4;
        ushort4 um, us;
        um.x = f2bf(vm.x); um.y = f2bf(vm.y); um.z = f2bf(vm.z); um.w = f2bf(vm.w);
        us.x = f2bf(vs.x); us.y = f2bf(vs.y); us.z = f2bf(vs.z); us.w = f2bf(vs.w);
        *(ushort4*)&tiles[sb] = um;
        *(ushort4*)&tiles[TILE_SH + sb] = us;
        // fused csum: quarter-sum of sigma + mu^2, quad-reduced
        float part = vs.x + vs.y + vs.z + vs.w
                   + vm.x * vm.x + vm.y * vm.y + vm.z * vm.z + vm.w * vm.w;
        part += __shfl_down(part, 2, 4);
        part += __shfl_down(part, 1, 4);
        if (c4 == 0) csum[pix] = part;
    }
    __syncthreads();

    // ---- 5x5 window sums: t12 per output pixel ----
    if (t < TH * TW) {
        int r = t >> 4, c = t & 15;
        float s = 0.f;
#pragma unroll
        for (int kh = 0; kh < KK; ++kh)
#pragma unroll
            for (int kw = 0; kw < KK; ++kw)
                s += csum[(r + kh) * IN_C + c + kw];
        t12s[t] = s;
    }
    __syncthreads();

    // ---- MFMA k-loop: 25 positions, K=16 channels each, 32x32x16 ----
    const int w   = t >> 6;          // wave id: rows 2w, 2w+1
    const int l   = t & 63;
    const int p   = l & 31;          // pixel index within wave's 32-px tile
    const int hi  = l >> 5;          // channel half for A/B k-elements
    const int pr  = p >> 4;          // local row 0/1
    const int pc  = p & 15;          // col 0..15

    const char* lds = (const char*)tiles;
    const int abase = ((2 * w + pr) * IN_C + pc) * (CPAD * 2) + hi * 16;

    const short8* Bmu8 = (const short8*)g_bmu;
    const short8* Bsq8 = (const short8*)g_bsq;

    f32x16 accm = {0.f}, accs = {0.f};
#pragma unroll
    for (int kh = 0; kh < KK; ++kh) {
#pragma unroll
        for (int kw = 0; kw < KK; ++kw) {
            const int ts  = kh * KK + kw;
            const int off = (kh * IN_C + kw) * (CPAD * 2);
            short8 am = *(const short8*)(lds + abase + off);
            short8 as = *(const short8*)(lds + abase + off + TILE_SH * 2);
            short8 bm = Bmu8[ts * 64 + l];
            short8 bs = Bsq8[ts * 64 + l];
            accm = __builtin_amdgcn_mfma_f32_32x32x16_bf16(am, bm, accm, 0, 0, 0);
            accs = __builtin_amdgcn_mfma_f32_32x32x16_bf16(as, bs, accs, 0, 0, 0);
        }
    }

    // ---- epilogue ----
    // D: col(channel) = l&31, row(pixel) = (reg&3) + 8*(reg>>2) + 4*hi
    const int n = l & 31;
    const float spwn = g_spw[n];
#pragma unroll
    for (int reg = 0; reg < 16; ++reg) {
        int rloc = (reg & 3) + 8 * (reg >> 2) + 4 * hi;   // pixel 0..31
        int lr = rloc >> 4, lc = rloc & 15;
        int ho = ho0 + 2 * w + lr;
        int wo = wo0 + lc;
        if (ho < HO && wo < WO) {
            float t12v = t12s[(2 * w + lr) * TW + lc];
            size_t base = (((size_t)b * HO + ho) * WO + wo) * KN + n;
            mu_out[base]  = accm[reg];
            sig_out[base] = softplusf(accs[reg] + t12v * spwn);
        }
    }
}

extern "C" void kernel_launch(void* const* d_in, const int* in_sizes, int n_in,
                              void* d_out, int out_size, void* d_ws, size_t ws_size,
                              hipStream_t stream) {
    const float* mu_in   = (const float*)d_in[0];
    const float* sig_in  = (const float*)d_in[1];
    const float* w_mu    = (const float*)d_in[2];
    const float* w_sigma = (const float*)d_in[3];

    float* out     = (float*)d_out;
    float* mu_out  = out;
    float* sig_out = out + (size_t)OUT_PLANE;
    float* kl_out  = out + 2 * (size_t)OUT_PLANE;

    (void)d_ws; (void)ws_size;

    prep_all<<<51, 256, 0, stream>>>(w_mu, w_sigma, kl_out);
    vdp_main<<<dim3(4, 8, NB), 256, 0, stream>>>(mu_in, sig_in, mu_out, sig_out);
}